// Round 5
// baseline (10179.296 us; speedup 1.0000x reference)
//
#include <hip/hip_runtime.h>
#include <math.h>

// Problem constants
#define EDIM 300
#define HDIM 512
#define TDIM 100
#define BDIM 256
#define KTOT 812      // E + H
#define KP   832      // padded K (26 * 32)
#define KHALF 416
#define NIT  13       // k-iterations per half
#define ENC  1024
#define NBLK 256

// Workspace layout (BYTE offsets), ws_size ~268MB
#define B_HHI   0u             // fp16 h hi [2 par][2 d][256][512]   1,048,576
#define B_HLO   1048576u       // fp16 h lo                          1,048,576
#define B_CNT   2097152u       // grid-barrier cnt/gen               256
#define B_WPF   2097408u       // fp16 W [2 d][2048 c'][832 k]       6,815,744
#define B_CTX   8913152u       // fp32 ctx [256][1024]               1,048,576
#define B_X1    9961728u
#define B_X2    11010304u
#define B_TWH   12058880u      // tail W hi bf16 [3][1024][1024]     6,291,456
#define B_TWL   18350336u
#define B_XSHI  24641792u      // fp16 x hi [2 d][256][100][300]     30,720,000
#define B_XSLO  55361792u      // -> ends 86,081,792

// LDS layout (persistent kernel): W slab [64 cols][832+8 pad] ushorts = 107,520 B
// A staging: [2 dbuf][2 half][2 hi/lo][64][40] ushorts = 40,960 B  -> 148,480 B
#define LW 0
#define LA(dbuf,half,hl) (107520 + (((((dbuf)*2)+(half))*2+(hl)) * 5120))
#define LRED 107520

typedef __attribute__((ext_vector_type(8))) short bf16x8;
typedef _Float16 f16x8 __attribute__((ext_vector_type(8)));
typedef __attribute__((ext_vector_type(4))) float f32x4;

__device__ __forceinline__ float fast_sigmoid(float x) {
    return 1.0f / (1.0f + __expf(-x));
}
__device__ __forceinline__ float fast_tanh(float x) {
    float t = __expf(2.0f * x);
    return 1.0f - 2.0f / (t + 1.0f);
}
// bf16 helpers (tail GEMM path)
__device__ __forceinline__ unsigned short bf16_rne(float v) {
    unsigned int u = __float_as_uint(v);
    unsigned int r = (u + 0x7fffu + ((u >> 16) & 1u)) >> 16;
    return (unsigned short)r;
}
__device__ __forceinline__ float bf16_to_f(unsigned short h) {
    return __uint_as_float(((unsigned int)h) << 16);
}
__device__ __forceinline__ void split2(float v, unsigned short& hi, unsigned short& lo) {
    hi = bf16_rne(v);
    lo = bf16_rne(v - bf16_to_f(hi));
}
// fp16 helpers (LSTM path)
__device__ __forceinline__ unsigned short f16_bits(float v) {
    _Float16 h = (_Float16)v;
    return *(unsigned short*)&h;
}
__device__ __forceinline__ float f16_val(unsigned short u) {
    _Float16 h = *(_Float16*)&u;
    return (float)h;
}
__device__ __forceinline__ void split_f16(float v, unsigned short& hi, unsigned short& lo) {
    hi = f16_bits(v);
    lo = f16_bits(v - f16_val(hi));
}

__global__ void zero_kernel(float* __restrict__ p, int n) {
    int i = blockIdx.x * blockDim.x + threadIdx.x;
    if (i < n) p[i] = 0.0f;
}

// ---- prep: permute + transpose lstm W -> fp16 [d][c'][k]; c' = G*64 + g*16 + (h&15)
__global__ __launch_bounds__(256) void prep_w_lstm(
    const float* __restrict__ WL, const float* __restrict__ WR, char* __restrict__ ws)
{
    __shared__ float tile[64 * 65];
    int bid = blockIdx.x;
    int d = bid / (13 * 32);
    int rem = bid - d * (13 * 32);
    int kt = rem >> 5;                // 0..12
    int ct = rem & 31;                // 0..31
    const int k0 = kt * 64;
    const float* W = d ? WR : WL;
    for (int pass = 0; pass < 16; ++pass) {
        int idx = pass * 256 + threadIdx.x;
        int kk = idx >> 6, c = idx & 63;
        int g = c >> 4, hl = c & 15;
        int col = g * HDIM + ct * 16 + hl;
        int kg = k0 + kk;
        tile[kk * 65 + c] = (kg < KTOT) ? W[(size_t)kg * 2048 + col] : 0.0f;
    }
    __syncthreads();
    unsigned short* wf = (unsigned short*)(ws + B_WPF) + (size_t)d * 2048 * KP;
    for (int pass = 0; pass < 16; ++pass) {
        int idx = pass * 256 + threadIdx.x;
        int c = idx >> 6, kk = idx & 63;
        wf[(size_t)(ct * 64 + c) * KP + k0 + kk] = f16_bits(tile[kk * 65 + c]);
    }
}

// ---- prep: transpose + split tail weights (bf16 hi/lo). l: 0=TW, 1=HW[0], 2=HW[1].
__global__ __launch_bounds__(256) void prep_w_tail(
    const float* __restrict__ TW, const float* __restrict__ HW, char* __restrict__ ws)
{
    __shared__ float tile[64 * 65];
    int bid = blockIdx.x;
    int l = bid / 256;
    int rem = bid - l * 256;
    int kt = rem >> 4, ct = rem & 15;
    const int k0 = kt * 64, n0 = ct * 64;
    const float* W = (l == 0) ? TW : (HW + (size_t)(l - 1) * ENC * ENC);
    for (int pass = 0; pass < 16; ++pass) {
        int idx = pass * 256 + threadIdx.x;
        int kk = idx >> 6, c = idx & 63;
        tile[kk * 65 + c] = W[(size_t)(k0 + kk) * ENC + n0 + c];
    }
    __syncthreads();
    unsigned short* wh = (unsigned short*)(ws + B_TWH) + (size_t)l * ENC * ENC;
    unsigned short* wl = (unsigned short*)(ws + B_TWL) + (size_t)l * ENC * ENC;
    for (int pass = 0; pass < 16; ++pass) {
        int idx = pass * 256 + threadIdx.x;
        int c = idx >> 6, kk = idx & 63;
        unsigned short hi, lo;
        split2(tile[kk * 65 + c], hi, lo);
        size_t o = (size_t)(n0 + c) * ENC + k0 + kk;
        wh[o] = hi;
        wl[o] = lo;
    }
}

// ---- prep: split x fp32 -> fp16 hi/lo
__global__ __launch_bounds__(256) void prep_x(
    const float* __restrict__ xL, const float* __restrict__ xR, char* __restrict__ ws)
{
    const long long NQ = 2LL * BDIM * TDIM * EDIM / 4;
    const long long N1 = (long long)BDIM * TDIM * EDIM;
    unsigned short* xh = (unsigned short*)(ws + B_XSHI);
    unsigned short* xl = (unsigned short*)(ws + B_XSLO);
    for (long long qi = blockIdx.x * blockDim.x + threadIdx.x; qi < NQ;
         qi += (long long)gridDim.x * blockDim.x) {
        long long i = qi * 4;
        const float* src = (i < N1) ? (xL + i) : (xR + (i - N1));
        float4 v = *(const float4*)src;
        ushort4 vh, vl;
        split_f16(v.x, vh.x, vl.x);
        split_f16(v.y, vh.y, vl.y);
        split_f16(v.z, vh.z, vl.z);
        split_f16(v.w, vh.w, vl.w);
        *(ushort4*)(xh + i) = vh;
        *(ushort4*)(xl + i) = vl;
    }
}

// ---- device-scope grid barrier (256 co-resident blocks; 1 block/CU forced by LDS)
__device__ __forceinline__ void grid_sync_dev(unsigned* cnt, unsigned* gen) {
    __threadfence();                 // release: make h stores agent-visible
    __syncthreads();
    if (threadIdx.x == 0) {
        unsigned g0 = __hip_atomic_load(gen, __ATOMIC_ACQUIRE, __HIP_MEMORY_SCOPE_AGENT);
        unsigned pos = __hip_atomic_fetch_add(cnt, 1u, __ATOMIC_ACQ_REL, __HIP_MEMORY_SCOPE_AGENT);
        if (pos == NBLK - 1u) {
            __hip_atomic_store(cnt, 0u, __ATOMIC_RELAXED, __HIP_MEMORY_SCOPE_AGENT);
            __hip_atomic_fetch_add(gen, 1u, __ATOMIC_RELEASE, __HIP_MEMORY_SCOPE_AGENT);
        } else {
            while (__hip_atomic_load(gen, __ATOMIC_ACQUIRE, __HIP_MEMORY_SCOPE_AGENT) == g0) {
                __builtin_amdgcn_s_sleep(2);
            }
        }
    }
    __syncthreads();
    __threadfence();                 // acquire: drop stale cached h
}

// ---- persistent LSTM: all 100 timesteps, both dirs, in one launch.
// grid 256 x 512 thr (8 waves = kh(2) x ms(4)). Block tile 64m x 64n.
// bid = mt + 8*ntile: blocks of one mt round-robin to one XCD (L2 locality hint only).
// W slab (fp16, single) lives in LDS for the whole kernel; A (x|h split fp16)
// double-buffered, 1 barrier per k-iteration. c state in registers.
__global__ __launch_bounds__(512, 1) void lstm_persistent(
    const int* __restrict__ lenL, const int* __restrict__ lenR,
    const float* __restrict__ bL, const float* __restrict__ bR,
    char* __restrict__ ws)
{
    __shared__ __align__(16) char smem[148480];

    const int bid   = blockIdx.x;
    const int mt    = bid & 7;            // 8 m-tiles (d x 4 brow)
    const int ntile = bid >> 3;           // 0..31
    const int n0    = ntile * 64;
    const int d     = mt >> 2;
    const int brow  = (mt & 3) * 64;

    const int* __restrict__ len    = d ? lenR : lenL;
    const float* __restrict__ bias = d ? bR : bL;

    unsigned* cnt = (unsigned*)(ws + B_CNT);
    unsigned* gen = (unsigned*)(ws + B_CNT) + 1;

    const unsigned short* __restrict__ Wp  = (const unsigned short*)(ws + B_WPF) + (size_t)d * 2048 * KP;
    const unsigned short* __restrict__ xsh = (const unsigned short*)(ws + B_XSHI);
    const unsigned short* __restrict__ xsl = (const unsigned short*)(ws + B_XSLO);
    float* __restrict__ ctx = (float*)(ws + B_CTX);

    const int tid  = threadIdx.x;
    const int l    = tid & 63;
    const int w    = tid >> 6;
    const int kh   = w >> 2;              // K-half
    const int ms   = w & 3;               // m-subtile
    const int fr   = l & 15;
    const int fg   = l >> 4;
    const int arow = tid >> 3;            // staging row 0..63
    const int q    = (tid & 7) * 4;       // staging k-quad

    // ---- load W slab into LDS once: 64 cols x 832 fp16 (208 quads/col)
    {
        const unsigned short* src = Wp + (size_t)n0 * KP;
        for (int i = 0; i < 26; ++i) {
            int idx = i * 512 + tid;              // 0..13311
            int col = idx / 208;
            int kq  = (idx - col * 208) * 4;
            *(ushort4*)(smem + LW + (col * 840 + kq) * 2) =
                *(const ushort4*)(src + (size_t)col * KP + kq);
        }
    }
    float c_arr[4] = {0.f, 0.f, 0.f, 0.f};        // cell state (kh0 threads)
    __syncthreads();

    const int grow = d * BDIM + brow + arow;      // global A row (with dir)

    for (int t = 0; t < TDIM; ++t) {
        const int par = t & 1;
        const unsigned short* __restrict__ hh_prev = (const unsigned short*)(ws + B_HHI) + (size_t)par * 262144;
        const unsigned short* __restrict__ hl_prev = (const unsigned short*)(ws + B_HLO) + (size_t)par * 262144;
        unsigned short* __restrict__ hh_next = (unsigned short*)(ws + B_HHI) + (size_t)(par ^ 1) * 262144;
        unsigned short* __restrict__ hl_next = (unsigned short*)(ws + B_HLO) + (size_t)(par ^ 1) * 262144;

        f32x4 acc[4] = {};

        ushort4 a0h, a0l, a1h, a1l;
        // stage iteration 'it' A data into regs
        auto ldA = [&](int it, ushort4& v0h, ushort4& v0l, ushort4& v1h, ushort4& v1l) {
            #pragma unroll
            for (int hf = 0; hf < 2; ++hf) {
                const int kg = hf * KHALF + it * 32 + q;
                ushort4 vh, vl;
                if (kg < EDIM) {
                    const size_t xo = ((size_t)grow * TDIM + t) * EDIM + kg;
                    vh = *(const ushort4*)(xsh + xo);
                    vl = *(const ushort4*)(xsl + xo);
                } else if (kg < KTOT) {
                    const size_t hidx = (size_t)grow * HDIM + (kg - EDIM);
                    vh = *(const ushort4*)(hh_prev + hidx);
                    vl = *(const ushort4*)(hl_prev + hidx);
                } else {
                    vh = make_ushort4(0, 0, 0, 0);
                    vl = make_ushort4(0, 0, 0, 0);
                }
                if (hf == 0) { v0h = vh; v0l = vl; } else { v1h = vh; v1l = vl; }
            }
        };
        auto stA = [&](int dbuf, ushort4 v0h, ushort4 v0l, ushort4 v1h, ushort4 v1l) {
            const int o = (arow * 40 + q) * 2;
            *(ushort4*)(smem + LA(dbuf, 0, 0) + o) = v0h;
            *(ushort4*)(smem + LA(dbuf, 0, 1) + o) = v0l;
            *(ushort4*)(smem + LA(dbuf, 1, 0) + o) = v1h;
            *(ushort4*)(smem + LA(dbuf, 1, 1) + o) = v1l;
        };

        ldA(0, a0h, a0l, a1h, a1l);
        stA(0, a0h, a0l, a1h, a1l);

        for (int it = 0; it < NIT; ++it) {
            if (it < NIT - 1) ldA(it + 1, a0h, a0l, a1h, a1l);
            __syncthreads();
            const int aoff = ((ms * 16 + fr) * 40 + fg * 8) * 2;
            const int cur = it & 1;
            const f16x8 ah = *(const f16x8*)(smem + LA(cur, kh, 0) + aoff);
            const f16x8 al = *(const f16x8*)(smem + LA(cur, kh, 1) + aoff);
            #pragma unroll
            for (int nf = 0; nf < 4; ++nf) {
                const f16x8 bv = *(const f16x8*)(smem + LW +
                    ((nf * 16 + fr) * 840 + kh * KHALF + it * 32 + fg * 8) * 2);
                acc[nf] = __builtin_amdgcn_mfma_f32_16x16x32_f16(ah, bv, acc[nf], 0, 0, 0);
                acc[nf] = __builtin_amdgcn_mfma_f32_16x16x32_f16(al, bv, acc[nf], 0, 0, 0);
            }
            if (it < NIT - 1) stA(cur ^ 1, a0h, a0l, a1h, a1l);
        }

        // ---- cross-half reduce (overlay on A staging region)
        __syncthreads();
        float* red = (float*)(smem + LRED);
        if (kh == 1) {
            #pragma unroll
            for (int nf = 0; nf < 4; ++nf)
                #pragma unroll
                for (int r = 0; r < 4; ++r)
                    red[(ms * 16 + fg * 4 + r) * 65 + nf * 16 + fr] = acc[nf][r];
        }
        __syncthreads();
        if (kh == 0) {
            #pragma unroll
            for (int nf = 0; nf < 4; ++nf)
                #pragma unroll
                for (int r = 0; r < 4; ++r)
                    acc[nf][r] += red[(ms * 16 + fg * 4 + r) * 65 + nf * 16 + fr];

            const int hcol = ntile * 16 + fr;
            const float bi  = bias[0 * HDIM + hcol];
            const float bj  = bias[1 * HDIM + hcol];
            const float bf_ = bias[2 * HDIM + hcol];
            const float bo  = bias[3 * HDIM + hcol];
            #pragma unroll
            for (int r = 0; r < 4; ++r) {
                const int row = brow + ms * 16 + fg * 4 + r;
                const float iv = acc[0][r] + bi;
                const float jv = acc[1][r] + bj;
                const float fv = acc[2][r] + bf_;
                const float ov = acc[3][r] + bo;
                const float c_new = c_arr[r] * fast_sigmoid(fv + 1.0f)
                                  + fast_sigmoid(iv) * fast_tanh(jv);
                const float h_new = fast_tanh(c_new) * fast_sigmoid(ov);
                c_arr[r] = c_new;
                const size_t hidx = (size_t)(d * BDIM + row) * HDIM + hcol;
                unsigned short hh, hl2;
                split_f16(h_new, hh, hl2);
                hh_next[hidx] = hh;
                hl_next[hidx] = hl2;
                if (t == len[row] - 1) {
                    ctx[(size_t)row * (2 * HDIM) + d * HDIM + hcol] = h_new;
                }
            }
        }
        grid_sync_dev(cnt, gen);
    }
}

// ---- tail GEMM: C = relu(A @ W), A [256,1024] fp32, W pre-split bf16 [1024 n][1024 k].
#define TL_AS_HI(hf) ((hf) * 5120)
#define TL_AS_LO(hf) (10240 + (hf) * 5120)
#define TL_BS_HI(hf) (20480 + (hf) * 5120)
#define TL_BS_LO(hf) (30720 + (hf) * 5120)

__global__ __launch_bounds__(512, 2) void gemm_relu_mfma(
    const float* __restrict__ A, const unsigned short* __restrict__ Wh,
    const unsigned short* __restrict__ Wl, float* __restrict__ C)
{
    const int ntile = blockIdx.x & 15;
    const int mt    = blockIdx.x >> 4;
    const int n0    = ntile * 64;
    const int m0    = mt * 64;

    __shared__ __align__(16) char smem[40960];

    const int tid  = threadIdx.x;
    const int l    = tid & 63;
    const int w    = tid >> 6;
    const int kh   = w >> 2;
    const int ms   = w & 3;
    const int fr   = l & 15;
    const int fg   = l >> 4;
    const int arow = tid >> 3;
    const int q    = (tid & 7) * 4;

    f32x4 acc[4] = {};

    for (int it = 0; it < 16; ++it) {
        #pragma unroll
        for (int hf = 0; hf < 2; ++hf) {
            const int kg = hf * 512 + it * 32 + q;
            const float4 v = *(const float4*)(A + (size_t)(m0 + arow) * ENC + kg);
            ushort4 vh, vl;
            split2(v.x, vh.x, vl.x);
            split2(v.y, vh.y, vl.y);
            split2(v.z, vh.z, vl.z);
            split2(v.w, vh.w, vl.w);
            *(ushort4*)(smem + TL_AS_HI(hf) + (arow * 40 + q) * 2) = vh;
            *(ushort4*)(smem + TL_AS_LO(hf) + (arow * 40 + q) * 2) = vl;
            const size_t wo = (size_t)(n0 + arow) * ENC + kg;
            *(ushort4*)(smem + TL_BS_HI(hf) + (arow * 40 + q) * 2) = *(const ushort4*)(Wh + wo);
            *(ushort4*)(smem + TL_BS_LO(hf) + (arow * 40 + q) * 2) = *(const ushort4*)(Wl + wo);
        }
        __syncthreads();
        const int aoff = ((ms * 16 + fr) * 40 + fg * 8) * 2;
        const bf16x8 ah = *(const bf16x8*)(smem + TL_AS_HI(kh) + aoff);
        const bf16x8 al = *(const bf16x8*)(smem + TL_AS_LO(kh) + aoff);
        #pragma unroll
        for (int nf = 0; nf < 4; ++nf) {
            const int boff = ((nf * 16 + fr) * 40 + fg * 8) * 2;
            const bf16x8 bh = *(const bf16x8*)(smem + TL_BS_HI(kh) + boff);
            const bf16x8 bl = *(const bf16x8*)(smem + TL_BS_LO(kh) + boff);
            acc[nf] = __builtin_amdgcn_mfma_f32_16x16x32_bf16(ah, bh, acc[nf], 0, 0, 0);
            acc[nf] = __builtin_amdgcn_mfma_f32_16x16x32_bf16(ah, bl, acc[nf], 0, 0, 0);
            acc[nf] = __builtin_amdgcn_mfma_f32_16x16x32_bf16(al, bh, acc[nf], 0, 0, 0);
        }
        __syncthreads();
    }

    float* red = (float*)smem;
    if (kh == 1) {
        #pragma unroll
        for (int nf = 0; nf < 4; ++nf)
            #pragma unroll
            for (int r = 0; r < 4; ++r)
                red[(ms * 16 + fg * 4 + r) * 65 + nf * 16 + fr] = acc[nf][r];
    }
    __syncthreads();
    if (kh == 0) {
        #pragma unroll
        for (int nf = 0; nf < 4; ++nf) {
            #pragma unroll
            for (int r = 0; r < 4; ++r) {
                float v = acc[nf][r] + red[(ms * 16 + fg * 4 + r) * 65 + nf * 16 + fr];
                v = v > 0.f ? v : 0.f;
                const int row = m0 + ms * 16 + fg * 4 + r;
                C[(size_t)row * ENC + n0 + nf * 16 + fr] = v;
            }
        }
    }
}

extern "C" void kernel_launch(void* const* d_in, const int* in_sizes, int n_in,
                              void* d_out, int out_size, void* d_ws, size_t ws_size,
                              hipStream_t stream) {
    const float* xL   = (const float*)d_in[0];
    const int*   lenL = (const int*)  d_in[1];
    const float* xR   = (const float*)d_in[2];
    const int*   lenR = (const int*)  d_in[3];
    const float* WL   = (const float*)d_in[4];
    const float* bL   = (const float*)d_in[5];
    const float* WR   = (const float*)d_in[6];
    const float* bR   = (const float*)d_in[7];
    const float* TW   = (const float*)d_in[8];
    const float* HW   = (const float*)d_in[9];
    char* ws   = (char*)d_ws;
    float* out = (float*)d_out;

    // zero h (both parities, hi+lo) + barrier counters: first 2,097,408 B
    zero_kernel<<<2049, 256, 0, stream>>>((float*)ws, 524352);
    prep_w_lstm<<<832, 256, 0, stream>>>(WL, WR, ws);
    prep_w_tail<<<768, 256, 0, stream>>>(TW, HW, ws);
    prep_x<<<2048, 256, 0, stream>>>(xL, xR, ws);

    lstm_persistent<<<NBLK, 512, 0, stream>>>(lenL, lenR, bL, bR, ws);

    float* ctx = (float*)(ws + B_CTX);
    float* x1  = (float*)(ws + B_X1);
    float* x2  = (float*)(ws + B_X2);
    const unsigned short* twh = (const unsigned short*)(ws + B_TWH);
    const unsigned short* twl = (const unsigned short*)(ws + B_TWL);
    gemm_relu_mfma<<<64, 512, 0, stream>>>(ctx, twh,                twl,                x1);
    gemm_relu_mfma<<<64, 512, 0, stream>>>(x1,  twh + 1024 * 1024, twl + 1024 * 1024,  x2);
    gemm_relu_mfma<<<64, 512, 0, stream>>>(x2,  twh + 2048 * 1024, twl + 2048 * 1024,  out);
}

// Round 6
// 8578.821 us; speedup vs baseline: 1.1866x; 1.1866x over previous
//
#include <hip/hip_runtime.h>
#include <math.h>

// Problem constants
#define EDIM 300
#define HDIM 512
#define TDIM 100
#define BDIM 256
#define KTOT 812      // E + H
#define KP   832      // padded K (26 * 32)
#define KHALF 416
#define NIT  13       // k-iterations per half
#define ENC  1024
#define NBLK 256
#define GRPB 32       // blocks per sync group (share one mt)

// Workspace layout (BYTE offsets), ws_size ~268MB
#define B_HHI   0u             // fp16 h hi [2 par][2 d][256][512]   1,048,576
#define B_HLO   1048576u       // fp16 h lo                          1,048,576
#define B_CNT   2097152u       // 8 group-barrier slots x 256 B      2,048
#define B_WPF   2099200u       // fp16 W [2 d][2048 c'][832 k]       6,815,744
#define B_CTX   8914944u       // fp32 ctx [256][1024]               1,048,576
#define B_X1    9963520u
#define B_X2    11012096u
#define B_TWH   12060672u      // tail W hi bf16 [3][1024][1024]     6,291,456
#define B_TWL   18352128u
#define B_XSHI  24643584u      // fp16 x hi [2 d][256][100][300]     30,720,000
#define B_XSLO  55363584u      // -> ends 86,083,584

// LDS layout (persistent kernel): W slab [64 cols][832+8 pad] ushorts = 107,520 B
// A staging: [2 dbuf][2 half][2 hi/lo][64][40] ushorts = 40,960 B  -> 148,480 B
#define LW 0
#define LA(dbuf,half,hl) (107520 + (((((dbuf)*2)+(half))*2+(hl)) * 5120))
#define LRED 107520

typedef __attribute__((ext_vector_type(8))) short bf16x8;
typedef _Float16 f16x8 __attribute__((ext_vector_type(8)));
typedef __attribute__((ext_vector_type(4))) float f32x4;

__device__ __forceinline__ float fast_sigmoid(float x) {
    return 1.0f / (1.0f + __expf(-x));
}
__device__ __forceinline__ float fast_tanh(float x) {
    float t = __expf(2.0f * x);
    return 1.0f - 2.0f / (t + 1.0f);
}
// bf16 helpers (tail GEMM path)
__device__ __forceinline__ unsigned short bf16_rne(float v) {
    unsigned int u = __float_as_uint(v);
    unsigned int r = (u + 0x7fffu + ((u >> 16) & 1u)) >> 16;
    return (unsigned short)r;
}
__device__ __forceinline__ float bf16_to_f(unsigned short h) {
    return __uint_as_float(((unsigned int)h) << 16);
}
__device__ __forceinline__ void split2(float v, unsigned short& hi, unsigned short& lo) {
    hi = bf16_rne(v);
    lo = bf16_rne(v - bf16_to_f(hi));
}
// fp16 helpers (LSTM path)
__device__ __forceinline__ unsigned short f16_bits(float v) {
    _Float16 h = (_Float16)v;
    return *(unsigned short*)&h;
}
__device__ __forceinline__ float f16_val(unsigned short u) {
    _Float16 h = *(_Float16*)&u;
    return (float)h;
}
__device__ __forceinline__ void split_f16(float v, unsigned short& hi, unsigned short& lo) {
    hi = f16_bits(v);
    lo = f16_bits(v - f16_val(hi));
}

__global__ void zero_kernel(float* __restrict__ p, int n) {
    int i = blockIdx.x * blockDim.x + threadIdx.x;
    if (i < n) p[i] = 0.0f;
}

// ---- prep: permute + transpose lstm W -> fp16 [d][c'][k]; c' = G*64 + g*16 + (h&15)
__global__ __launch_bounds__(256) void prep_w_lstm(
    const float* __restrict__ WL, const float* __restrict__ WR, char* __restrict__ ws)
{
    __shared__ float tile[64 * 65];
    int bid = blockIdx.x;
    int d = bid / (13 * 32);
    int rem = bid - d * (13 * 32);
    int kt = rem >> 5;                // 0..12
    int ct = rem & 31;                // 0..31
    const int k0 = kt * 64;
    const float* W = d ? WR : WL;
    for (int pass = 0; pass < 16; ++pass) {
        int idx = pass * 256 + threadIdx.x;
        int kk = idx >> 6, c = idx & 63;
        int g = c >> 4, hl = c & 15;
        int col = g * HDIM + ct * 16 + hl;
        int kg = k0 + kk;
        tile[kk * 65 + c] = (kg < KTOT) ? W[(size_t)kg * 2048 + col] : 0.0f;
    }
    __syncthreads();
    unsigned short* wf = (unsigned short*)(ws + B_WPF) + (size_t)d * 2048 * KP;
    for (int pass = 0; pass < 16; ++pass) {
        int idx = pass * 256 + threadIdx.x;
        int c = idx >> 6, kk = idx & 63;
        wf[(size_t)(ct * 64 + c) * KP + k0 + kk] = f16_bits(tile[kk * 65 + c]);
    }
}

// ---- prep: transpose + split tail weights (bf16 hi/lo). l: 0=TW, 1=HW[0], 2=HW[1].
__global__ __launch_bounds__(256) void prep_w_tail(
    const float* __restrict__ TW, const float* __restrict__ HW, char* __restrict__ ws)
{
    __shared__ float tile[64 * 65];
    int bid = blockIdx.x;
    int l = bid / 256;
    int rem = bid - l * 256;
    int kt = rem >> 4, ct = rem & 15;
    const int k0 = kt * 64, n0 = ct * 64;
    const float* W = (l == 0) ? TW : (HW + (size_t)(l - 1) * ENC * ENC);
    for (int pass = 0; pass < 16; ++pass) {
        int idx = pass * 256 + threadIdx.x;
        int kk = idx >> 6, c = idx & 63;
        tile[kk * 65 + c] = W[(size_t)(k0 + kk) * ENC + n0 + c];
    }
    __syncthreads();
    unsigned short* wh = (unsigned short*)(ws + B_TWH) + (size_t)l * ENC * ENC;
    unsigned short* wl = (unsigned short*)(ws + B_TWL) + (size_t)l * ENC * ENC;
    for (int pass = 0; pass < 16; ++pass) {
        int idx = pass * 256 + threadIdx.x;
        int c = idx >> 6, kk = idx & 63;
        unsigned short hi, lo;
        split2(tile[kk * 65 + c], hi, lo);
        size_t o = (size_t)(n0 + c) * ENC + k0 + kk;
        wh[o] = hi;
        wl[o] = lo;
    }
}

// ---- prep: split x fp32 -> fp16 hi/lo
__global__ __launch_bounds__(256) void prep_x(
    const float* __restrict__ xL, const float* __restrict__ xR, char* __restrict__ ws)
{
    const long long NQ = 2LL * BDIM * TDIM * EDIM / 4;
    const long long N1 = (long long)BDIM * TDIM * EDIM;
    unsigned short* xh = (unsigned short*)(ws + B_XSHI);
    unsigned short* xl = (unsigned short*)(ws + B_XSLO);
    for (long long qi = blockIdx.x * blockDim.x + threadIdx.x; qi < NQ;
         qi += (long long)gridDim.x * blockDim.x) {
        long long i = qi * 4;
        const float* src = (i < N1) ? (xL + i) : (xR + (i - N1));
        float4 v = *(const float4*)src;
        ushort4 vh, vl;
        split_f16(v.x, vh.x, vl.x);
        split_f16(v.y, vh.y, vl.y);
        split_f16(v.z, vh.z, vl.z);
        split_f16(v.w, vh.w, vl.w);
        *(ushort4*)(xh + i) = vh;
        *(ushort4*)(xl + i) = vl;
    }
}

// ---- per-group barrier: 32 blocks sharing one mt. Slot layout per group
// (256 B): cnt @ +0, gen @ +128 (separate cachelines: RMW line != spin line).
__device__ __forceinline__ void group_sync(char* gbase, int grp) {
    __threadfence();                 // release h stores (agent scope)
    __syncthreads();
    if (threadIdx.x == 0) {
        unsigned* cnt = (unsigned*)(gbase + grp * 256);
        unsigned* gen = (unsigned*)(gbase + grp * 256 + 128);
        unsigned g0 = __hip_atomic_load(gen, __ATOMIC_RELAXED, __HIP_MEMORY_SCOPE_AGENT);
        unsigned pos = __hip_atomic_fetch_add(cnt, 1u, __ATOMIC_ACQ_REL, __HIP_MEMORY_SCOPE_AGENT);
        if (pos == GRPB - 1u) {
            __hip_atomic_store(cnt, 0u, __ATOMIC_RELAXED, __HIP_MEMORY_SCOPE_AGENT);
            __hip_atomic_store(gen, g0 + 1u, __ATOMIC_RELEASE, __HIP_MEMORY_SCOPE_AGENT);
        } else {
            while (__hip_atomic_load(gen, __ATOMIC_ACQUIRE, __HIP_MEMORY_SCOPE_AGENT) == g0) {
                __builtin_amdgcn_s_sleep(8);
            }
        }
    }
    __syncthreads();
    __threadfence();                 // acquire: drop stale h
}

// ---- persistent LSTM: all 100 timesteps, both dirs, one launch.
// grid 256 x 512 thr (8 waves = kh(2) x ms(4)). Block tile 64m x 64n.
// mt = bid&7: the 32 blocks sharing an mt form one sync group (and, under
// round-robin dispatch, one XCD -> group atomics + h traffic stay near one L2).
__global__ __launch_bounds__(512, 1) void lstm_persistent(
    const int* __restrict__ lenL, const int* __restrict__ lenR,
    const float* __restrict__ bL, const float* __restrict__ bR,
    char* __restrict__ ws)
{
    __shared__ __align__(16) char smem[148480];

    const int bid   = blockIdx.x;
    const int mt    = bid & 7;            // 8 m-tiles (d x 4 brow) = sync group
    const int ntile = bid >> 3;           // 0..31
    const int n0    = ntile * 64;
    const int d     = mt >> 2;
    const int brow  = (mt & 3) * 64;

    const int* __restrict__ len    = d ? lenR : lenL;
    const float* __restrict__ bias = d ? bR : bL;

    const unsigned short* __restrict__ Wp  = (const unsigned short*)(ws + B_WPF) + (size_t)d * 2048 * KP;
    const unsigned short* __restrict__ xsh = (const unsigned short*)(ws + B_XSHI);
    const unsigned short* __restrict__ xsl = (const unsigned short*)(ws + B_XSLO);
    float* __restrict__ ctx = (float*)(ws + B_CTX);

    const int tid  = threadIdx.x;
    const int l    = tid & 63;
    const int w    = tid >> 6;
    const int kh   = w >> 2;              // K-half
    const int ms   = w & 3;               // m-subtile
    const int fr   = l & 15;
    const int fg   = l >> 4;
    const int arow = tid >> 3;            // staging row 0..63
    const int q    = (tid & 7) * 4;       // staging k-quad

    // ---- load W slab into LDS once: 64 cols x 832 fp16 (208 quads/col)
    {
        const unsigned short* src = Wp + (size_t)n0 * KP;
        for (int i = 0; i < 26; ++i) {
            int idx = i * 512 + tid;              // 0..13311
            int col = idx / 208;
            int kq  = (idx - col * 208) * 4;
            *(ushort4*)(smem + LW + (col * 840 + kq) * 2) =
                *(const ushort4*)(src + (size_t)col * KP + kq);
        }
    }
    float c_arr[4] = {0.f, 0.f, 0.f, 0.f};        // cell state (kh0 threads)
    __syncthreads();

    const int grow = d * BDIM + brow + arow;      // global A row (with dir)

    for (int t = 0; t < TDIM; ++t) {
        const int par = t & 1;
        const unsigned short* __restrict__ hh_prev = (const unsigned short*)(ws + B_HHI) + (size_t)par * 262144;
        const unsigned short* __restrict__ hl_prev = (const unsigned short*)(ws + B_HLO) + (size_t)par * 262144;
        unsigned short* __restrict__ hh_next = (unsigned short*)(ws + B_HHI) + (size_t)(par ^ 1) * 262144;
        unsigned short* __restrict__ hl_next = (unsigned short*)(ws + B_HLO) + (size_t)(par ^ 1) * 262144;

        f32x4 acc[4] = {};

        ushort4 a0h, a0l, a1h, a1l;
        // stage iteration 'it' A data into regs
        auto ldA = [&](int it, ushort4& v0h, ushort4& v0l, ushort4& v1h, ushort4& v1l) {
            #pragma unroll
            for (int hf = 0; hf < 2; ++hf) {
                const int kg = hf * KHALF + it * 32 + q;
                ushort4 vh, vl;
                if (kg < EDIM) {
                    const size_t xo = ((size_t)grow * TDIM + t) * EDIM + kg;
                    vh = *(const ushort4*)(xsh + xo);
                    vl = *(const ushort4*)(xsl + xo);
                } else if (kg < KTOT) {
                    const size_t hidx = (size_t)grow * HDIM + (kg - EDIM);
                    vh = *(const ushort4*)(hh_prev + hidx);
                    vl = *(const ushort4*)(hl_prev + hidx);
                } else {
                    vh = make_ushort4(0, 0, 0, 0);
                    vl = make_ushort4(0, 0, 0, 0);
                }
                if (hf == 0) { v0h = vh; v0l = vl; } else { v1h = vh; v1l = vl; }
            }
        };
        auto stA = [&](int dbuf, ushort4 v0h, ushort4 v0l, ushort4 v1h, ushort4 v1l) {
            const int o = (arow * 40 + q) * 2;
            *(ushort4*)(smem + LA(dbuf, 0, 0) + o) = v0h;
            *(ushort4*)(smem + LA(dbuf, 0, 1) + o) = v0l;
            *(ushort4*)(smem + LA(dbuf, 1, 0) + o) = v1h;
            *(ushort4*)(smem + LA(dbuf, 1, 1) + o) = v1l;
        };

        ldA(0, a0h, a0l, a1h, a1l);
        stA(0, a0h, a0l, a1h, a1l);

        for (int it = 0; it < NIT; ++it) {
            if (it < NIT - 1) ldA(it + 1, a0h, a0l, a1h, a1l);
            __syncthreads();
            const int aoff = ((ms * 16 + fr) * 40 + fg * 8) * 2;
            const int cur = it & 1;
            const f16x8 ah = *(const f16x8*)(smem + LA(cur, kh, 0) + aoff);
            const f16x8 al = *(const f16x8*)(smem + LA(cur, kh, 1) + aoff);
            #pragma unroll
            for (int nf = 0; nf < 4; ++nf) {
                const f16x8 bv = *(const f16x8*)(smem + LW +
                    ((nf * 16 + fr) * 840 + kh * KHALF + it * 32 + fg * 8) * 2);
                acc[nf] = __builtin_amdgcn_mfma_f32_16x16x32_f16(ah, bv, acc[nf], 0, 0, 0);
                acc[nf] = __builtin_amdgcn_mfma_f32_16x16x32_f16(al, bv, acc[nf], 0, 0, 0);
            }
            if (it < NIT - 1) stA(cur ^ 1, a0h, a0l, a1h, a1l);
        }

        // ---- cross-half reduce (overlay on A staging region)
        __syncthreads();
        float* red = (float*)(smem + LRED);
        if (kh == 1) {
            #pragma unroll
            for (int nf = 0; nf < 4; ++nf)
                #pragma unroll
                for (int r = 0; r < 4; ++r)
                    red[(ms * 16 + fg * 4 + r) * 65 + nf * 16 + fr] = acc[nf][r];
        }
        __syncthreads();
        if (kh == 0) {
            #pragma unroll
            for (int nf = 0; nf < 4; ++nf)
                #pragma unroll
                for (int r = 0; r < 4; ++r)
                    acc[nf][r] += red[(ms * 16 + fg * 4 + r) * 65 + nf * 16 + fr];

            const int hcol = ntile * 16 + fr;
            const float bi  = bias[0 * HDIM + hcol];
            const float bj  = bias[1 * HDIM + hcol];
            const float bf_ = bias[2 * HDIM + hcol];
            const float bo  = bias[3 * HDIM + hcol];
            #pragma unroll
            for (int r = 0; r < 4; ++r) {
                const int row = brow + ms * 16 + fg * 4 + r;
                const float iv = acc[0][r] + bi;
                const float jv = acc[1][r] + bj;
                const float fv = acc[2][r] + bf_;
                const float ov = acc[3][r] + bo;
                const float c_new = c_arr[r] * fast_sigmoid(fv + 1.0f)
                                  + fast_sigmoid(iv) * fast_tanh(jv);
                const float h_new = fast_tanh(c_new) * fast_sigmoid(ov);
                c_arr[r] = c_new;
                const size_t hidx = (size_t)(d * BDIM + row) * HDIM + hcol;
                unsigned short hh, hl2;
                split_f16(h_new, hh, hl2);
                hh_next[hidx] = hh;
                hl_next[hidx] = hl2;
                if (t == len[row] - 1) {
                    ctx[(size_t)row * (2 * HDIM) + d * HDIM + hcol] = h_new;
                }
            }
        }
        if (t < TDIM - 1) group_sync(ws + B_CNT, mt);
    }
}

// ---- tail GEMM: C = relu(A @ W), A [256,1024] fp32, W pre-split bf16 [1024 n][1024 k].
#define TL_AS_HI(hf) ((hf) * 5120)
#define TL_AS_LO(hf) (10240 + (hf) * 5120)
#define TL_BS_HI(hf) (20480 + (hf) * 5120)
#define TL_BS_LO(hf) (30720 + (hf) * 5120)

__global__ __launch_bounds__(512, 2) void gemm_relu_mfma(
    const float* __restrict__ A, const unsigned short* __restrict__ Wh,
    const unsigned short* __restrict__ Wl, float* __restrict__ C)
{
    const int ntile = blockIdx.x & 15;
    const int mt    = blockIdx.x >> 4;
    const int n0    = ntile * 64;
    const int m0    = mt * 64;

    __shared__ __align__(16) char smem[40960];

    const int tid  = threadIdx.x;
    const int l    = tid & 63;
    const int w    = tid >> 6;
    const int kh   = w >> 2;
    const int ms   = w & 3;
    const int fr   = l & 15;
    const int fg   = l >> 4;
    const int arow = tid >> 3;
    const int q    = (tid & 7) * 4;

    f32x4 acc[4] = {};

    for (int it = 0; it < 16; ++it) {
        #pragma unroll
        for (int hf = 0; hf < 2; ++hf) {
            const int kg = hf * 512 + it * 32 + q;
            const float4 v = *(const float4*)(A + (size_t)(m0 + arow) * ENC + kg);
            ushort4 vh, vl;
            split2(v.x, vh.x, vl.x);
            split2(v.y, vh.y, vl.y);
            split2(v.z, vh.z, vl.z);
            split2(v.w, vh.w, vl.w);
            *(ushort4*)(smem + TL_AS_HI(hf) + (arow * 40 + q) * 2) = vh;
            *(ushort4*)(smem + TL_AS_LO(hf) + (arow * 40 + q) * 2) = vl;
            const size_t wo = (size_t)(n0 + arow) * ENC + kg;
            *(ushort4*)(smem + TL_BS_HI(hf) + (arow * 40 + q) * 2) = *(const ushort4*)(Wh + wo);
            *(ushort4*)(smem + TL_BS_LO(hf) + (arow * 40 + q) * 2) = *(const ushort4*)(Wl + wo);
        }
        __syncthreads();
        const int aoff = ((ms * 16 + fr) * 40 + fg * 8) * 2;
        const bf16x8 ah = *(const bf16x8*)(smem + TL_AS_HI(kh) + aoff);
        const bf16x8 al = *(const bf16x8*)(smem + TL_AS_LO(kh) + aoff);
        #pragma unroll
        for (int nf = 0; nf < 4; ++nf) {
            const int boff = ((nf * 16 + fr) * 40 + fg * 8) * 2;
            const bf16x8 bh = *(const bf16x8*)(smem + TL_BS_HI(kh) + boff);
            const bf16x8 bl = *(const bf16x8*)(smem + TL_BS_LO(kh) + boff);
            acc[nf] = __builtin_amdgcn_mfma_f32_16x16x32_bf16(ah, bh, acc[nf], 0, 0, 0);
            acc[nf] = __builtin_amdgcn_mfma_f32_16x16x32_bf16(ah, bl, acc[nf], 0, 0, 0);
            acc[nf] = __builtin_amdgcn_mfma_f32_16x16x32_bf16(al, bh, acc[nf], 0, 0, 0);
        }
        __syncthreads();
    }

    float* red = (float*)smem;
    if (kh == 1) {
        #pragma unroll
        for (int nf = 0; nf < 4; ++nf)
            #pragma unroll
            for (int r = 0; r < 4; ++r)
                red[(ms * 16 + fg * 4 + r) * 65 + nf * 16 + fr] = acc[nf][r];
    }
    __syncthreads();
    if (kh == 0) {
        #pragma unroll
        for (int nf = 0; nf < 4; ++nf) {
            #pragma unroll
            for (int r = 0; r < 4; ++r) {
                float v = acc[nf][r] + red[(ms * 16 + fg * 4 + r) * 65 + nf * 16 + fr];
                v = v > 0.f ? v : 0.f;
                const int row = m0 + ms * 16 + fg * 4 + r;
                C[(size_t)row * ENC + n0 + nf * 16 + fr] = v;
            }
        }
    }
}

extern "C" void kernel_launch(void* const* d_in, const int* in_sizes, int n_in,
                              void* d_out, int out_size, void* d_ws, size_t ws_size,
                              hipStream_t stream) {
    const float* xL   = (const float*)d_in[0];
    const int*   lenL = (const int*)  d_in[1];
    const float* xR   = (const float*)d_in[2];
    const int*   lenR = (const int*)  d_in[3];
    const float* WL   = (const float*)d_in[4];
    const float* bL   = (const float*)d_in[5];
    const float* WR   = (const float*)d_in[6];
    const float* bR   = (const float*)d_in[7];
    const float* TW   = (const float*)d_in[8];
    const float* HW   = (const float*)d_in[9];
    char* ws   = (char*)d_ws;
    float* out = (float*)d_out;

    // zero h (both parities, hi+lo) + 8 barrier slots: first 2,099,200 B
    zero_kernel<<<2050, 256, 0, stream>>>((float*)ws, 524800);
    prep_w_lstm<<<832, 256, 0, stream>>>(WL, WR, ws);
    prep_w_tail<<<768, 256, 0, stream>>>(TW, HW, ws);
    prep_x<<<2048, 256, 0, stream>>>(xL, xR, ws);

    lstm_persistent<<<NBLK, 512, 0, stream>>>(lenL, lenR, bL, bR, ws);

    float* ctx = (float*)(ws + B_CTX);
    float* x1  = (float*)(ws + B_X1);
    float* x2  = (float*)(ws + B_X2);
    const unsigned short* twh = (const unsigned short*)(ws + B_TWH);
    const unsigned short* twl = (const unsigned short*)(ws + B_TWL);
    gemm_relu_mfma<<<64, 512, 0, stream>>>(ctx, twh,                twl,                x1);
    gemm_relu_mfma<<<64, 512, 0, stream>>>(x1,  twh + 1024 * 1024, twl + 1024 * 1024,  x2);
    gemm_relu_mfma<<<64, 512, 0, stream>>>(x2,  twh + 2048 * 1024, twl + 2048 * 1024,  out);
}

// Round 7
// 1260.469 us; speedup vs baseline: 8.0758x; 6.8061x over previous
//
#include <hip/hip_runtime.h>
#include <math.h>

// Problem constants
#define EDIM 300
#define HDIM 512
#define TDIM 100
#define BDIM 256
#define KTOT 812      // E + H
#define KP   832      // padded K (26 * 32)
#define KHALF 416
#define NIT  13       // k-iterations (each covers 32 of both K-halves)
#define ENC  1024
#define NBLK 256

// Workspace layout (BYTE offsets), ws_size ~268MB
#define B_C     0u             // c fp32 [2][256][512]               1,048,576
#define B_HHI   1048576u       // fp16 h hi [2 par][2 d][256][512]   1,048,576
#define B_HLO   2097152u       // fp16 h lo                          1,048,576
#define B_WPF   3145728u       // fp16 W [2 d][2048 c'][832 k]       6,815,744
#define B_CTX   9961472u       // fp32 ctx [256][1024]               1,048,576
#define B_X1    11010048u
#define B_X2    12058624u
#define B_TWH   13107200u      // tail W hi bf16 [3][1024][1024]     6,291,456
#define B_TWL   19398656u      // tail W lo                          6,291,456
#define B_XSHI  25690112u      // fp16 x hi [2 d][256][100][300]     30,720,000
#define B_XSLO  56410112u      // -> ends 87,130,112

// LDS layout (step kernel): W slab [64 cols][832+8 pad] ushorts = 107,520 B
// A staging: [2 dbuf][2 half][2 hi/lo][64][40] ushorts = 40,960 B  -> 148,480 B
#define LW 0
#define LA(dbuf,half,hl) (107520 + (((((dbuf)*2)+(half))*2+(hl)) * 5120))
#define LRED 107520

typedef __attribute__((ext_vector_type(8))) short bf16x8;
typedef _Float16 f16x8 __attribute__((ext_vector_type(8)));
typedef __attribute__((ext_vector_type(4))) float f32x4;

__device__ __forceinline__ float fast_sigmoid(float x) {
    return 1.0f / (1.0f + __expf(-x));
}
__device__ __forceinline__ float fast_tanh(float x) {
    float t = __expf(2.0f * x);
    return 1.0f - 2.0f / (t + 1.0f);
}
// bf16 helpers (tail GEMM path)
__device__ __forceinline__ unsigned short bf16_rne(float v) {
    unsigned int u = __float_as_uint(v);
    unsigned int r = (u + 0x7fffu + ((u >> 16) & 1u)) >> 16;
    return (unsigned short)r;
}
__device__ __forceinline__ float bf16_to_f(unsigned short h) {
    return __uint_as_float(((unsigned int)h) << 16);
}
__device__ __forceinline__ void split2(float v, unsigned short& hi, unsigned short& lo) {
    hi = bf16_rne(v);
    lo = bf16_rne(v - bf16_to_f(hi));
}
// fp16 helpers (LSTM path)
__device__ __forceinline__ unsigned short f16_bits(float v) {
    _Float16 h = (_Float16)v;
    return *(unsigned short*)&h;
}
__device__ __forceinline__ float f16_val(unsigned short u) {
    _Float16 h = *(_Float16*)&u;
    return (float)h;
}
__device__ __forceinline__ void split_f16(float v, unsigned short& hi, unsigned short& lo) {
    hi = f16_bits(v);
    lo = f16_bits(v - f16_val(hi));
}

__global__ void zero_kernel(float* __restrict__ p, int n) {
    int i = blockIdx.x * blockDim.x + threadIdx.x;
    if (i < n) p[i] = 0.0f;
}

// ---- prep: permute + transpose lstm W -> fp16 [d][c'][k]; c' = G*64 + g*16 + (h&15)
__global__ __launch_bounds__(256) void prep_w_lstm(
    const float* __restrict__ WL, const float* __restrict__ WR, char* __restrict__ ws)
{
    __shared__ float tile[64 * 65];
    int bid = blockIdx.x;
    int d = bid / (13 * 32);
    int rem = bid - d * (13 * 32);
    int kt = rem >> 5;                // 0..12
    int ct = rem & 31;                // 0..31
    const int k0 = kt * 64;
    const float* W = d ? WR : WL;
    for (int pass = 0; pass < 16; ++pass) {
        int idx = pass * 256 + threadIdx.x;
        int kk = idx >> 6, c = idx & 63;
        int g = c >> 4, hl = c & 15;
        int col = g * HDIM + ct * 16 + hl;
        int kg = k0 + kk;
        tile[kk * 65 + c] = (kg < KTOT) ? W[(size_t)kg * 2048 + col] : 0.0f;
    }
    __syncthreads();
    unsigned short* wf = (unsigned short*)(ws + B_WPF) + (size_t)d * 2048 * KP;
    for (int pass = 0; pass < 16; ++pass) {
        int idx = pass * 256 + threadIdx.x;
        int c = idx >> 6, kk = idx & 63;
        wf[(size_t)(ct * 64 + c) * KP + k0 + kk] = f16_bits(tile[kk * 65 + c]);
    }
}

// ---- prep: transpose + split tail weights (bf16 hi/lo). l: 0=TW, 1=HW[0], 2=HW[1].
__global__ __launch_bounds__(256) void prep_w_tail(
    const float* __restrict__ TW, const float* __restrict__ HW, char* __restrict__ ws)
{
    __shared__ float tile[64 * 65];
    int bid = blockIdx.x;
    int l = bid / 256;
    int rem = bid - l * 256;
    int kt = rem >> 4, ct = rem & 15;
    const int k0 = kt * 64, n0 = ct * 64;
    const float* W = (l == 0) ? TW : (HW + (size_t)(l - 1) * ENC * ENC);
    for (int pass = 0; pass < 16; ++pass) {
        int idx = pass * 256 + threadIdx.x;
        int kk = idx >> 6, c = idx & 63;
        tile[kk * 65 + c] = W[(size_t)(k0 + kk) * ENC + n0 + c];
    }
    __syncthreads();
    unsigned short* wh = (unsigned short*)(ws + B_TWH) + (size_t)l * ENC * ENC;
    unsigned short* wl = (unsigned short*)(ws + B_TWL) + (size_t)l * ENC * ENC;
    for (int pass = 0; pass < 16; ++pass) {
        int idx = pass * 256 + threadIdx.x;
        int c = idx >> 6, kk = idx & 63;
        unsigned short hi, lo;
        split2(tile[kk * 65 + c], hi, lo);
        size_t o = (size_t)(n0 + c) * ENC + k0 + kk;
        wh[o] = hi;
        wl[o] = lo;
    }
}

// ---- prep: split x fp32 -> fp16 hi/lo
__global__ __launch_bounds__(256) void prep_x(
    const float* __restrict__ xL, const float* __restrict__ xR, char* __restrict__ ws)
{
    const long long NQ = 2LL * BDIM * TDIM * EDIM / 4;
    const long long N1 = (long long)BDIM * TDIM * EDIM;
    unsigned short* xh = (unsigned short*)(ws + B_XSHI);
    unsigned short* xl = (unsigned short*)(ws + B_XSLO);
    for (long long qi = blockIdx.x * blockDim.x + threadIdx.x; qi < NQ;
         qi += (long long)gridDim.x * blockDim.x) {
        long long i = qi * 4;
        const float* src = (i < N1) ? (xL + i) : (xR + (i - N1));
        float4 v = *(const float4*)src;
        ushort4 vh, vl;
        split_f16(v.x, vh.x, vl.x);
        split_f16(v.y, vh.y, vl.y);
        split_f16(v.z, vh.z, vl.z);
        split_f16(v.w, vh.w, vl.w);
        *(ushort4*)(xh + i) = vh;
        *(ushort4*)(xl + i) = vl;
    }
}

struct APack { ushort4 h0h, h0l, h1h, h1l; };

// ---- One LSTM timestep (per-launch; kernel boundary = global sync).
// grid 256 x 512 thr (8 waves = kh(2) x ms(4)). Block tile 64m x 64n.
// ntile from bid&7 => same-ntile blocks share one XCD's L2 for the W slab.
// W slab (fp16) loaded to LDS once per launch; A 2-deep register-prefetched.
__global__ __launch_bounds__(512, 1) void lstm_step_f16(
    const int* __restrict__ lenL, const int* __restrict__ lenR,
    const float* __restrict__ bL, const float* __restrict__ bR,
    char* __restrict__ ws, int t, int par)
{
    __shared__ __align__(16) char smem[148480];

    const int bid   = blockIdx.x;
    const int ntile = (bid & 7) * 4 + ((bid >> 3) & 3);   // 0..31, XCD-aligned
    const int mt    = bid >> 5;                           // 0..7
    const int n0    = ntile * 64;
    const int d     = mt >> 2;
    const int brow  = (mt & 3) * 64;

    const int* __restrict__ len    = d ? lenR : lenL;
    const float* __restrict__ bias = d ? bR : bL;

    float* __restrict__ cbuf = (float*)(ws + B_C);
    const unsigned short* __restrict__ hh_prev = (const unsigned short*)(ws + B_HHI) + (size_t)par * 262144;
    const unsigned short* __restrict__ hl_prev = (const unsigned short*)(ws + B_HLO) + (size_t)par * 262144;
    unsigned short* __restrict__ hh_next = (unsigned short*)(ws + B_HHI) + (size_t)(par ^ 1) * 262144;
    unsigned short* __restrict__ hl_next = (unsigned short*)(ws + B_HLO) + (size_t)(par ^ 1) * 262144;
    const unsigned short* __restrict__ Wp  = (const unsigned short*)(ws + B_WPF) + (size_t)d * 2048 * KP;
    const unsigned short* __restrict__ xsh = (const unsigned short*)(ws + B_XSHI);
    const unsigned short* __restrict__ xsl = (const unsigned short*)(ws + B_XSLO);
    float* __restrict__ ctx = (float*)(ws + B_CTX);

    const int tid  = threadIdx.x;
    const int l    = tid & 63;
    const int w    = tid >> 6;
    const int kh   = w >> 2;              // K-half
    const int ms   = w & 3;               // m-subtile
    const int fr   = l & 15;
    const int fg   = l >> 4;
    const int arow = tid >> 3;            // staging row 0..63
    const int q    = (tid & 7) * 4;       // staging k-quad

    // ---- early scalar prefetches (epilogue operands)
    const int hcol = ntile * 16 + fr;
    const int row0 = brow + ms * 16 + fg * 4;            // 4 consecutive rows
    const float bi  = bias[0 * HDIM + hcol];
    const float bj  = bias[1 * HDIM + hcol];
    const float bf_ = bias[2 * HDIM + hcol];
    const float bo  = bias[3 * HDIM + hcol];
    const int4 len4 = *(const int4*)(len + row0);
    float c_arr[4];
    {
        const size_t cb = (size_t)(d * BDIM + row0) * HDIM + hcol;
        c_arr[0] = cbuf[cb];
        c_arr[1] = cbuf[cb + HDIM];
        c_arr[2] = cbuf[cb + 2 * HDIM];
        c_arr[3] = cbuf[cb + 3 * HDIM];
    }

    // ---- load W slab into LDS: 64 cols x 832 fp16 (208 quads/col)
    {
        const unsigned short* src = Wp + (size_t)n0 * KP;
        #pragma unroll
        for (int i = 0; i < 26; ++i) {
            int idx = i * 512 + tid;              // 0..13311
            int col = idx / 208;
            int kq  = (idx - col * 208) * 4;
            *(ushort4*)(smem + LW + (col * 840 + kq) * 2) =
                *(const ushort4*)(src + (size_t)col * KP + kq);
        }
    }

    const int grow = d * BDIM + brow + arow;      // global A row (with dir)

    // A loader: iteration 'it' covers k = {kh*416 + it*32 + q} for both halves
    auto ldA = [&](int it, APack& p) {
        #pragma unroll
        for (int hf = 0; hf < 2; ++hf) {
            const int kg = hf * KHALF + it * 32 + q;
            ushort4 vh, vl;
            if (kg < EDIM) {
                const size_t xo = ((size_t)grow * TDIM + t) * EDIM + kg;
                vh = *(const ushort4*)(xsh + xo);
                vl = *(const ushort4*)(xsl + xo);
            } else if (kg < KTOT) {
                const size_t hidx = (size_t)grow * HDIM + (kg - EDIM);
                vh = *(const ushort4*)(hh_prev + hidx);
                vl = *(const ushort4*)(hl_prev + hidx);
            } else {
                vh = make_ushort4(0, 0, 0, 0);
                vl = make_ushort4(0, 0, 0, 0);
            }
            if (hf == 0) { p.h0h = vh; p.h0l = vl; } else { p.h1h = vh; p.h1l = vl; }
        }
    };
    auto stA = [&](int dbuf, const APack& p) {
        const int o = (arow * 40 + q) * 2;
        *(ushort4*)(smem + LA(dbuf, 0, 0) + o) = p.h0h;
        *(ushort4*)(smem + LA(dbuf, 0, 1) + o) = p.h0l;
        *(ushort4*)(smem + LA(dbuf, 1, 0) + o) = p.h1h;
        *(ushort4*)(smem + LA(dbuf, 1, 1) + o) = p.h1l;
    };

    f32x4 acc[4] = {};
    APack pf[2];

    ldA(0, pf[0]);
    stA(0, pf[0]);
    ldA(1, pf[1]);

    #pragma unroll
    for (int it = 0; it < NIT; ++it) {
        if (it + 2 < NIT) ldA(it + 2, pf[it & 1]);    // 2-deep prefetch
        __syncthreads();
        const int cur = it & 1;
        const int aoff = ((ms * 16 + fr) * 40 + fg * 8) * 2;
        const f16x8 ah = *(const f16x8*)(smem + LA(cur, kh, 0) + aoff);
        const f16x8 al = *(const f16x8*)(smem + LA(cur, kh, 1) + aoff);
        #pragma unroll
        for (int nf = 0; nf < 4; ++nf) {
            const f16x8 bv = *(const f16x8*)(smem + LW +
                ((nf * 16 + fr) * 840 + kh * KHALF + it * 32 + fg * 8) * 2);
            acc[nf] = __builtin_amdgcn_mfma_f32_16x16x32_f16(ah, bv, acc[nf], 0, 0, 0);
            acc[nf] = __builtin_amdgcn_mfma_f32_16x16x32_f16(al, bv, acc[nf], 0, 0, 0);
        }
        if (it + 1 < NIT) stA(cur ^ 1, pf[(it + 1) & 1]);
    }

    // ---- cross-half reduce (overlay on A staging region)
    __syncthreads();
    float* red = (float*)(smem + LRED);
    if (kh == 1) {
        #pragma unroll
        for (int nf = 0; nf < 4; ++nf)
            #pragma unroll
            for (int r = 0; r < 4; ++r)
                red[(ms * 16 + fg * 4 + r) * 65 + nf * 16 + fr] = acc[nf][r];
    }
    __syncthreads();
    if (kh == 0) {
        #pragma unroll
        for (int nf = 0; nf < 4; ++nf)
            #pragma unroll
            for (int r = 0; r < 4; ++r)
                acc[nf][r] += red[(ms * 16 + fg * 4 + r) * 65 + nf * 16 + fr];

        const int lens[4] = { len4.x, len4.y, len4.z, len4.w };
        #pragma unroll
        for (int r = 0; r < 4; ++r) {
            const int row = row0 + r;
            const float iv = acc[0][r] + bi;
            const float jv = acc[1][r] + bj;
            const float fv = acc[2][r] + bf_;
            const float ov = acc[3][r] + bo;
            const float c_new = c_arr[r] * fast_sigmoid(fv + 1.0f)
                              + fast_sigmoid(iv) * fast_tanh(jv);
            const float h_new = fast_tanh(c_new) * fast_sigmoid(ov);
            const size_t hidx = (size_t)(d * BDIM + row) * HDIM + hcol;
            cbuf[hidx] = c_new;
            unsigned short hh, hl2;
            split_f16(h_new, hh, hl2);
            hh_next[hidx] = hh;
            hl_next[hidx] = hl2;
            if (t == lens[r] - 1) {
                ctx[(size_t)row * (2 * HDIM) + d * HDIM + hcol] = h_new;
            }
        }
    }
}

// ---- tail GEMM: C = relu(A @ W), A [256,1024] fp32, W pre-split bf16 [1024 n][1024 k].
#define TL_AS_HI(hf) ((hf) * 5120)
#define TL_AS_LO(hf) (10240 + (hf) * 5120)
#define TL_BS_HI(hf) (20480 + (hf) * 5120)
#define TL_BS_LO(hf) (30720 + (hf) * 5120)

__global__ __launch_bounds__(512, 2) void gemm_relu_mfma(
    const float* __restrict__ A, const unsigned short* __restrict__ Wh,
    const unsigned short* __restrict__ Wl, float* __restrict__ C)
{
    const int ntile = blockIdx.x & 15;
    const int mt    = blockIdx.x >> 4;
    const int n0    = ntile * 64;
    const int m0    = mt * 64;

    __shared__ __align__(16) char smem[40960];

    const int tid  = threadIdx.x;
    const int l    = tid & 63;
    const int w    = tid >> 6;
    const int kh   = w >> 2;
    const int ms   = w & 3;
    const int fr   = l & 15;
    const int fg   = l >> 4;
    const int arow = tid >> 3;
    const int q    = (tid & 7) * 4;

    f32x4 acc[4] = {};

    for (int it = 0; it < 16; ++it) {
        #pragma unroll
        for (int hf = 0; hf < 2; ++hf) {
            const int kg = hf * 512 + it * 32 + q;
            const float4 v = *(const float4*)(A + (size_t)(m0 + arow) * ENC + kg);
            ushort4 vh, vl;
            split2(v.x, vh.x, vl.x);
            split2(v.y, vh.y, vl.y);
            split2(v.z, vh.z, vl.z);
            split2(v.w, vh.w, vl.w);
            *(ushort4*)(smem + TL_AS_HI(hf) + (arow * 40 + q) * 2) = vh;
            *(ushort4*)(smem + TL_AS_LO(hf) + (arow * 40 + q) * 2) = vl;
            const size_t wo = (size_t)(n0 + arow) * ENC + kg;
            *(ushort4*)(smem + TL_BS_HI(hf) + (arow * 40 + q) * 2) = *(const ushort4*)(Wh + wo);
            *(ushort4*)(smem + TL_BS_LO(hf) + (arow * 40 + q) * 2) = *(const ushort4*)(Wl + wo);
        }
        __syncthreads();
        const int aoff = ((ms * 16 + fr) * 40 + fg * 8) * 2;
        const bf16x8 ah = *(const bf16x8*)(smem + TL_AS_HI(kh) + aoff);
        const bf16x8 al = *(const bf16x8*)(smem + TL_AS_LO(kh) + aoff);
        #pragma unroll
        for (int nf = 0; nf < 4; ++nf) {
            const int boff = ((nf * 16 + fr) * 40 + fg * 8) * 2;
            const bf16x8 bh = *(const bf16x8*)(smem + TL_BS_HI(kh) + boff);
            const bf16x8 bl = *(const bf16x8*)(smem + TL_BS_LO(kh) + boff);
            acc[nf] = __builtin_amdgcn_mfma_f32_16x16x32_bf16(ah, bh, acc[nf], 0, 0, 0);
            acc[nf] = __builtin_amdgcn_mfma_f32_16x16x32_bf16(ah, bl, acc[nf], 0, 0, 0);
            acc[nf] = __builtin_amdgcn_mfma_f32_16x16x32_bf16(al, bh, acc[nf], 0, 0, 0);
        }
        __syncthreads();
    }

    float* red = (float*)smem;
    if (kh == 1) {
        #pragma unroll
        for (int nf = 0; nf < 4; ++nf)
            #pragma unroll
            for (int r = 0; r < 4; ++r)
                red[(ms * 16 + fg * 4 + r) * 65 + nf * 16 + fr] = acc[nf][r];
    }
    __syncthreads();
    if (kh == 0) {
        #pragma unroll
        for (int nf = 0; nf < 4; ++nf) {
            #pragma unroll
            for (int r = 0; r < 4; ++r) {
                float v = acc[nf][r] + red[(ms * 16 + fg * 4 + r) * 65 + nf * 16 + fr];
                v = v > 0.f ? v : 0.f;
                const int row = m0 + ms * 16 + fg * 4 + r;
                C[(size_t)row * ENC + n0 + nf * 16 + fr] = v;
            }
        }
    }
}

extern "C" void kernel_launch(void* const* d_in, const int* in_sizes, int n_in,
                              void* d_out, int out_size, void* d_ws, size_t ws_size,
                              hipStream_t stream) {
    const float* xL   = (const float*)d_in[0];
    const int*   lenL = (const int*)  d_in[1];
    const float* xR   = (const float*)d_in[2];
    const int*   lenR = (const int*)  d_in[3];
    const float* WL   = (const float*)d_in[4];
    const float* bL   = (const float*)d_in[5];
    const float* WR   = (const float*)d_in[6];
    const float* bR   = (const float*)d_in[7];
    const float* TW   = (const float*)d_in[8];
    const float* HW   = (const float*)d_in[9];
    char* ws   = (char*)d_ws;
    float* out = (float*)d_out;

    // zero c + h (both parities, hi+lo): first 3 MB
    zero_kernel<<<3072, 256, 0, stream>>>((float*)ws, 786432);
    prep_w_lstm<<<832, 256, 0, stream>>>(WL, WR, ws);
    prep_w_tail<<<768, 256, 0, stream>>>(TW, HW, ws);
    prep_x<<<2048, 256, 0, stream>>>(xL, xR, ws);

    for (int t = 0; t < TDIM; ++t) {
        lstm_step_f16<<<NBLK, 512, 0, stream>>>(lenL, lenR, bL, bR, ws, t, t & 1);
    }

    float* ctx = (float*)(ws + B_CTX);
    float* x1  = (float*)(ws + B_X1);
    float* x2  = (float*)(ws + B_X2);
    const unsigned short* twh = (const unsigned short*)(ws + B_TWH);
    const unsigned short* twl = (const unsigned short*)(ws + B_TWL);
    gemm_relu_mfma<<<64, 512, 0, stream>>>(ctx, twh,                twl,                x1);
    gemm_relu_mfma<<<64, 512, 0, stream>>>(x1,  twh + 1024 * 1024, twl + 1024 * 1024,  x2);
    gemm_relu_mfma<<<64, 512, 0, stream>>>(x2,  twh + 2048 * 1024, twl + 2048 * 1024,  out);
}